// Round 7
// baseline (46.592 us; speedup 1.0000x reference)
//
#include <hip/hip_runtime.h>
#include <math.h>

// ---------------------------------------------------------------------------
// DirectVoxGO Raw2Alpha + Alphas2Weights (forward), fused per-ray scan.
//
// outputs (concatenated in d_out, float32):
//   weights[n_pts]         = alpha_j * T_j,  T_j = prod_{k<j} (1-alpha_k)
//   alphainv_last[n_rays]  = prod over ray of (1-alpha)
//
// Structure: one wave64 = 4 rays, one 16-lane group per ray, 12 consecutive
// elements per lane (capacity 192 >> len ~ Poisson(128)). Common path is
// loop-free: 3x float4 load -> in-lane prefix-product -> 4-step DPP
// scan-within-16 -> T-chain -> nontemporal stores. Rare rays >192-3 samples
// take extra iterations (correct, ~never executed).
//   fast path (interval == 0.5): (1-alpha) = rsqrt(1 + exp2(y)),
//       y = (density+shift)*log2e
//   general path: (1-alpha) = exp2(-c * (max(y,0) + log2(1 + 2^-|y|)))
// ---------------------------------------------------------------------------

#define LOG2E 1.4426950408889634f
#define EPL   12              // elements per lane
#define CAP   (16 * EPL)      // per-ray capacity per iteration = 192

__device__ __forceinline__ float exp2f_(float x) { return __builtin_amdgcn_exp2f(x); }
__device__ __forceinline__ float log2f_(float x) { return __builtin_amdgcn_logf(x); }
__device__ __forceinline__ float rsqf_(float x)  { return __builtin_amdgcn_rsqf(x); }

typedef float vf4 __attribute__((ext_vector_type(4)));

// Multiplicative DPP scan step: I *= row_shr-moved I, identity 1.0 where the
// source slot is invalid (row start). row_shr never crosses a 16-lane row,
// so each 16-lane group scans independently.
#define MUL_DPP(I, CTRL)                                                      \
    do {                                                                      \
        int _t = __builtin_amdgcn_update_dpp(                                 \
            0x3f800000 /*1.0f*/, __builtin_bit_cast(int, (I)),                \
            (CTRL), 0xF, 0xF, false);                                         \
        (I) *= __builtin_bit_cast(float, _t);                                 \
    } while (0)

// Kernel 1: start[r] = first index i with ray_id[i] >= r, r in [0, n_rays].
// ray_id sorted ascending; empty rays get start[r] == start[r+1].
__global__ void seg_starts_kernel(const int* __restrict__ ray_id,
                                  int n_pts, int n_rays,
                                  int* __restrict__ start) {
    const int i = (blockIdx.x * blockDim.x + threadIdx.x) * 4;
    if (i >= n_pts) return;
    int prev = (i == 0) ? -1 : ray_id[i - 1];
    if (i + 4 <= n_pts) {
        const int4 v = *reinterpret_cast<const int4*>(ray_id + i);
        for (int q = prev + 1; q <= v.x; ++q) start[q] = i;
        for (int q = v.x + 1;  q <= v.y; ++q) start[q] = i + 1;
        for (int q = v.y + 1;  q <= v.z; ++q) start[q] = i + 2;
        for (int q = v.z + 1;  q <= v.w; ++q) start[q] = i + 3;
        prev = v.w;
    } else {
        for (int j = 0; j < 4 && i + j < n_pts; ++j) {
            const int c = ray_id[i + j];
            for (int q = prev + 1; q <= c; ++q) start[q] = i + j;
            prev = c;
        }
    }
    if (i + 4 >= n_pts) {
        for (int q = prev + 1; q <= n_rays; ++q) start[q] = n_pts;
    }
}

// Kernel 2: 4 rays per wave (16-lane groups), 12 elems/lane, one-shot.
__global__ void alpha_weights_kernel(const float* __restrict__ density,
                                     const float* __restrict__ shift_p,
                                     const float* __restrict__ interval_p,
                                     const int* __restrict__ start,
                                     float* __restrict__ weights,
                                     float* __restrict__ alphainv_last,
                                     int n_rays, int n_pts) {
    const int lane = threadIdx.x & 63;
    const int wid  = threadIdx.x >> 6;
    const int wave = blockIdx.x * (blockDim.x >> 6) + wid;
    const int g    = lane >> 4;      // group (ray within wave)
    const int tl   = lane & 15;      // lane within group
    const int ray  = wave * 4 + g;
    if (wave * 4 >= n_rays) return;

    const float shift = shift_p[0];
    const float c     = interval_p[0];
    const float sh2   = shift * LOG2E;
    const float negc  = -c;
    const bool  fast  = (c == 0.5f);            // wave-uniform

    const int sidx = (ray     < n_rays) ? ray     : n_rays;
    const int eidx = (ray + 1 < n_rays) ? ray + 1 : n_rays;
    const int s = start[sidx];
    const int e = start[eidx];                  // ray>=n_rays -> s==e (empty)
    const unsigned len = (unsigned)(e - s);

    float carry = 1.0f;                         // running transmittance
    int base = s & ~3;                          // 16B-aligned span start
    while (base < e) {                          // runs once except freak rays
        const int idx0 = base + tl * EPL;

        // ---- load 12 consecutive elements (3x float4), guarded per quad ----
        float d[EPL];
        #pragma unroll
        for (int j = 0; j < 3; ++j) {
            const int qidx = idx0 + 4 * j;
            if (qidx < e && qidx + 4 <= n_pts) {
                const float4 v = *reinterpret_cast<const float4*>(density + qidx);
                d[4*j+0] = v.x; d[4*j+1] = v.y; d[4*j+2] = v.z; d[4*j+3] = v.w;
            } else {
                #pragma unroll
                for (int k = 0; k < 4; ++k) {
                    const int ii = qidx + k;
                    d[4*j+k] = (ii < e && ii < n_pts) ? density[ii] : 0.0f;
                }
            }
        }

        // ---- (1 - alpha) per element, identity 1.0 outside [s,e) ----
        float a[EPL];
        #pragma unroll
        for (int k = 0; k < EPL; ++k) {
            const unsigned rel = (unsigned)(idx0 + k - s);  // wraps below s
            const float y = fmaf(d[k], LOG2E, sh2);
            float av;
            if (fast) {
                av = rsqf_(1.0f + exp2f_(y));
            } else {
                const float sp = fmaxf(y, 0.f) + log2f_(1.f + exp2f_(-fabsf(y)));
                av = exp2f_(negc * sp);
            }
            a[k] = (rel < len) ? av : 1.0f;
        }

        // ---- in-lane inclusive prefix products ----
        float q[EPL];
        q[0] = a[0];
        #pragma unroll
        for (int k = 1; k < EPL; ++k) q[k] = q[k-1] * a[k];

        // ---- 16-lane inclusive multiplicative scan of lane totals (DPP) ----
        float I = q[EPL-1];
        MUL_DPP(I, 0x111);   // row_shr:1
        MUL_DPP(I, 0x112);   // row_shr:2
        MUL_DPP(I, 0x114);   // row_shr:4
        MUL_DPP(I, 0x118);   // row_shr:8  -> inclusive within 16-lane group

        // exclusive: previous lane's inclusive (identity 1.0 at row start)
        const int ex_i = __builtin_amdgcn_update_dpp(
            0x3f800000, __builtin_bit_cast(int, I), 0x111, 0xF, 0xF, false);
        float T = carry * __builtin_bit_cast(float, ex_i);  // T before elem 0

        // ---- weights: w_k = T_k - T_{k+1}, nontemporal quad stores ----
        #pragma unroll
        for (int j = 0; j < 3; ++j) {
            const int qidx = idx0 + 4 * j;
            const float T1 = T  * a[4*j+0]; const float w0 = T  - T1;
            const float T2 = T1 * a[4*j+1]; const float w1 = T1 - T2;
            const float T3 = T2 * a[4*j+2]; const float w2 = T2 - T3;
            const float T4 = T3 * a[4*j+3]; const float w3 = T3 - T4;
            if (qidx >= s && qidx + 4 <= e) {       // fully-valid fast path
                vf4 w = { w0, w1, w2, w3 };
                __builtin_nontemporal_store(w, reinterpret_cast<vf4*>(weights + qidx));
            } else {
                const unsigned rel = (unsigned)(qidx - s);
                if (rel     < len) weights[qidx]     = w0;
                if (rel + 1 < len) weights[qidx + 1] = w1;
                if (rel + 2 < len) weights[qidx + 2] = w2;
                if (rel + 3 < len) weights[qidx + 3] = w3;
            }
            T = T4;
        }

        base += CAP;
        if (base < e) {
            // freak ray (>~189 samples): broadcast group total to all lanes
            // via ds_swizzle lane -> (lane & 16) | 15  (within 32-lane halves)
            const int bi = __builtin_amdgcn_ds_swizzle(
                __builtin_bit_cast(int, I), 0x1F0);
            carry *= __builtin_bit_cast(float, bi);
        } else {
            carry *= I;          // only lane 15's value is used afterwards
        }
    }

    // lane 15 of each group holds the full-ray product (empty rays: 1.0)
    if (tl == 15 && ray < n_rays) alphainv_last[ray] = carry;
}

extern "C" void kernel_launch(void* const* d_in, const int* in_sizes, int n_in,
                              void* d_out, int out_size, void* d_ws, size_t ws_size,
                              hipStream_t stream) {
    const float* density  = (const float*)d_in[0];
    const float* shift    = (const float*)d_in[1];   // 1-element array
    const float* interval = (const float*)d_in[2];   // 1-element array
    const int*   ray_id   = (const int*)d_in[3];
    const int n_pts  = in_sizes[0];
    const int n_rays = out_size - n_pts;

    int*   start    = (int*)d_ws;                 // (n_rays + 1) ints of scratch
    float* weights  = (float*)d_out;              // [n_pts]
    float* alphainv = (float*)d_out + n_pts;      // [n_rays]

    {
        const int block = 256;
        const int work  = (n_pts + 3) / 4;
        const int grid  = (work + block - 1) / block;
        seg_starts_kernel<<<grid, block, 0, stream>>>(ray_id, n_pts, n_rays, start);
    }
    {
        const int block = 256;                    // 4 waves -> 16 rays per block
        const int rays_per_block = 16;
        const int grid = (n_rays + rays_per_block - 1) / rays_per_block;
        alpha_weights_kernel<<<grid, block, 0, stream>>>(
            density, shift, interval, start, weights, alphainv, n_rays, n_pts);
    }
}

// Round 9
// 26.906 us; speedup vs baseline: 1.7317x; 1.7317x over previous
//
#include <hip/hip_runtime.h>
#include <math.h>

// ---------------------------------------------------------------------------
// DirectVoxGO Raw2Alpha + Alphas2Weights (forward), single fused kernel.
//
// outputs (concatenated in d_out, float32):
//   weights[n_pts]         = alpha_j * T_j,  T_j = prod_{k<j} (1-alpha_k)
//   alphainv_last[n_rays]  = prod over ray of (1-alpha)  (empty rays -> 1.0)
//
// Structure: 1 block (256 thr) per 1024 consecutive points, 4 pts/thread
// (full int4/float4 coalescing). Segmented multiplicative scan:
//   thread-local fold -> wave64 DPP (value,flag) scan -> 4-wave LDS combine.
// Cross-block carry: ray len << 1024, so the head ray starts within a <=256
// window before `base`; each block recomputes that partial product locally
// (no inter-block sync; deterministic; graph-safe).
//   fast path (interval == 0.5): (1-alpha) = rsqrt(1 + exp2(y)),
//       y = (density+shift)*log2e
//   general path: (1-alpha) = exp2(-c * (max(y,0) + log2(1 + 2^-|y|)))
// ---------------------------------------------------------------------------

#define LOG2E 1.4426950408889634f

typedef float vf4 __attribute__((ext_vector_type(4)));

__device__ __forceinline__ float exp2f_(float x) { return __builtin_amdgcn_exp2f(x); }
__device__ __forceinline__ float log2f_(float x) { return __builtin_amdgcn_logf(x); }
__device__ __forceinline__ float rsqf_(float x)  { return __builtin_amdgcn_rsqf(x); }

__device__ __forceinline__ float oma(float d, float sh2, float negc, bool fast) {
    const float y = fmaf(d, LOG2E, sh2);
    if (fast) return rsqf_(1.0f + exp2f_(y));
    const float sp = fmaxf(y, 0.f) + log2f_(1.f + exp2f_(-fabsf(y)));
    return exp2f_(negc * sp);
}

// Segmented-scan DPP step: combine src (earlier lanes, identity (1,0) when
// out-of-row/masked) into (V,F):  V = F ? V : Vs*V;  F |= Fs.
// CTRL/RM must be compile-time constants for __builtin_amdgcn_update_dpp.
template <int CTRL, int RM>
__device__ __forceinline__ void seg_step(float& V, int& F) {
    const int vs_i = __builtin_amdgcn_update_dpp(
        0x3f800000, __builtin_bit_cast(int, V), CTRL, RM, 0xF, false);
    const int fs = __builtin_amdgcn_update_dpp(0, F, CTRL, RM, 0xF, false);
    const float vs = __builtin_bit_cast(float, vs_i);
    V = F ? V : vs * V;
    F = F | fs;
}

// Full-wave product, result broadcast to all lanes.
__device__ __forceinline__ float wave_prod_bcast(float x) {
#define STEPP(CTRL, RM)                                                        \
    { int t_ = __builtin_amdgcn_update_dpp(0x3f800000,                         \
          __builtin_bit_cast(int, x), CTRL, RM, 0xF, false);                   \
      x *= __builtin_bit_cast(float, t_); }
    STEPP(0x111, 0xF) STEPP(0x112, 0xF) STEPP(0x114, 0xF)
    STEPP(0x118, 0xF) STEPP(0x142, 0xA) STEPP(0x143, 0xC)
#undef STEPP
    return __builtin_bit_cast(float,
        __builtin_amdgcn_readlane(__builtin_bit_cast(int, x), 63));
}

// Full-wave int max, result broadcast to all lanes.
__device__ __forceinline__ int wave_imax_bcast(int x) {
#define STEPM(CTRL, RM)                                                        \
    { int t_ = __builtin_amdgcn_update_dpp((int)0x80000000, x, CTRL, RM,       \
                                           0xF, false);                        \
      x = (x > t_) ? x : t_; }
    STEPM(0x111, 0xF) STEPM(0x112, 0xF) STEPM(0x114, 0xF)
    STEPM(0x118, 0xF) STEPM(0x142, 0xA) STEPM(0x143, 0xC)
#undef STEPM
    return __builtin_amdgcn_readlane(x, 63);
}

__global__ void __launch_bounds__(256)
fused_alpha_weights(const float* __restrict__ density,
                    const int*   __restrict__ ray_id,
                    const float* __restrict__ shift_p,
                    const float* __restrict__ interval_p,
                    float* __restrict__ weights,
                    float* __restrict__ alphainv,
                    int n_pts, int n_rays) {
    __shared__ int   s_first[256];
    __shared__ int   s_last[256];
    __shared__ float s_wv[4];
    __shared__ int   s_wf[4];
    __shared__ float s_red[4];
    __shared__ int   s_redi[4];

    const int t    = threadIdx.x;
    const int lane = t & 63;
    const int wid  = t >> 6;
    const int base = blockIdx.x << 10;          // 1024 points per block
    const int idx0 = base + t * 4;

    const float shift = shift_p[0];
    const float c     = interval_p[0];
    const float sh2   = shift * LOG2E;
    const float negc  = -c;
    const bool  fast  = (c == 0.5f);

    // ---- phase 1: load own quad (coalesced int4 + float4) ----
    int4 rid;  float4 den;
    bool v0, v1, v2, v3;
    if (idx0 + 4 <= n_pts) {
        rid = *reinterpret_cast<const int4*>(ray_id + idx0);
        den = *reinterpret_cast<const float4*>(density + idx0);
        v0 = v1 = v2 = v3 = true;
    } else {
        int r[4]; float d[4];
        #pragma unroll
        for (int k = 0; k < 4; ++k) {
            const int i = idx0 + k;
            const bool vv = (i < n_pts);
            r[k] = vv ? ray_id[i] : n_rays;     // sentinel past-end ray
            d[k] = vv ? density[i] : 0.0f;
        }
        rid = make_int4(r[0], r[1], r[2], r[3]);
        den = make_float4(d[0], d[1], d[2], d[3]);
        v0 = (idx0 < n_pts); v1 = (idx0 + 1 < n_pts);
        v2 = (idx0 + 2 < n_pts); v3 = (idx0 + 3 < n_pts);
    }

    s_first[t] = rid.x;
    s_last[t]  = rid.w;
    __syncthreads();

    // id following element 3 (for segment-end detection)
    int next3;
    if (t < 255) next3 = s_first[t + 1];
    else         next3 = (base + 1024 < n_pts) ? ray_id[base + 1024] : n_rays;

    // ---- phase 2: head carry = product over [s0, base) of straddling ray ----
    float carry0  = 1.0f;
    int   head_new = 1;                          // does a ray start at `base`?
    if (base > 0) {
        const int rid_first = s_first[0];        // ray active at `base`
        int lo = base, s0 = 0;
        for (;;) {
            const int wstart = lo - 256;
            const int i = wstart + t;
            const int v = (i >= 0) ? ray_id[i] : -1;   // i<0 always "differs"
            const int cand = (v != rid_first) ? t : -1;
            const int wm = wave_imax_bcast(cand);
            if (lane == 0) s_redi[wid] = wm;
            __syncthreads();
            int m = s_redi[0];
            m = (s_redi[1] > m) ? s_redi[1] : m;
            m = (s_redi[2] > m) ? s_redi[2] : m;
            m = (s_redi[3] > m) ? s_redi[3] : m;
            __syncthreads();
            if (m >= 0) { s0 = wstart + m + 1; break; }
            lo = wstart;                          // freak ray: walk further back
        }
        head_new = (s0 == base) ? 1 : 0;
        for (int off = s0; off < base; off += 256) {
            const int i = off + t;
            const float aa = (i < base) ? oma(density[i], sh2, negc, fast) : 1.0f;
            const float wp = wave_prod_bcast(aa);
            if (lane == 0) s_red[wid] = wp;
            __syncthreads();
            carry0 *= s_red[0] * s_red[1] * s_red[2] * s_red[3];
            __syncthreads();
        }
    }

    // ---- phase 3: per-element (1-alpha) and segment flags ----
    float a0 = oma(den.x, sh2, negc, fast);
    float a1 = oma(den.y, sh2, negc, fast);
    float a2 = oma(den.z, sh2, negc, fast);
    float a3 = oma(den.w, sh2, negc, fast);
    a0 = v0 ? a0 : 1.0f;  a1 = v1 ? a1 : 1.0f;
    a2 = v2 ? a2 : 1.0f;  a3 = v3 ? a3 : 1.0f;

    const int prev_last = (t > 0) ? s_last[t - 1] : (head_new ? -1 : rid.x);
    const int f0 = (rid.x != prev_last);
    const int f1 = (rid.y != rid.x);
    const int f2 = (rid.z != rid.y);
    const int f3 = (rid.w != rid.z);

    // ---- phase 4: thread-local (V,F) fold over 4 elements ----
    float V = a0;  int F = f0;
    V = f1 ? a1 : V * a1;  F |= f1;
    V = f2 ? a2 : V * a2;  F |= f2;
    V = f3 ? a3 : V * a3;  F |= f3;

    // ---- phase 5: wave64 inclusive segmented scan of thread pairs (DPP) ----
    float Vi = V;  int Fi = F;
    seg_step<0x111, 0xF>(Vi, Fi);   // row_shr:1
    seg_step<0x112, 0xF>(Vi, Fi);   // row_shr:2
    seg_step<0x114, 0xF>(Vi, Fi);   // row_shr:4
    seg_step<0x118, 0xF>(Vi, Fi);   // row_shr:8
    seg_step<0x142, 0xA>(Vi, Fi);   // row_bcast:15 -> rows 1,3
    seg_step<0x143, 0xC>(Vi, Fi);   // row_bcast:31 -> rows 2,3

    // exclusive pair for this thread (within wave)
    float Vx = __shfl_up(Vi, 1, 64);
    int   Fx = __shfl_up(Fi, 1, 64);
    if (lane == 0) { Vx = 1.0f; Fx = 0; }

    // ---- phase 6: cross-wave combine via LDS ----
    if (lane == 63) { s_wv[wid] = Vi; s_wf[wid] = Fi; }
    __syncthreads();
    float Ev = carry0;                 // fold block head carry as leading pair
    #pragma unroll
    for (int w2 = 0; w2 < 3; ++w2) {
        if (w2 < wid) {
            const float bv = s_wv[w2];  const int bf = s_wf[w2];
            Ev = bf ? bv : Ev * bv;
        }
    }
    Ev = Fx ? Vx : Ev * Vx;            // exclusive transmittance at elem 0

    // ---- phase 7: T chain, weights, alphainv ----
    const float T0 = f0 ? 1.0f : Ev;
    const float T1 = f1 ? 1.0f : T0 * a0;
    const float T2 = f2 ? 1.0f : T1 * a1;
    const float T3 = f3 ? 1.0f : T2 * a2;
    const float e0 = T0 * a0, e1 = T1 * a1, e2 = T2 * a2, e3 = T3 * a3;

    if (idx0 + 4 <= n_pts) {
        vf4 w = { T0 - e0, T1 - e1, T2 - e2, T3 - e3 };
        __builtin_nontemporal_store(w, reinterpret_cast<vf4*>(weights + idx0));
    } else {
        if (v0) weights[idx0]     = T0 - e0;
        if (v1) weights[idx0 + 1] = T1 - e1;
        if (v2) weights[idx0 + 2] = T2 - e2;
        if (v3) weights[idx0 + 3] = T3 - e3;
    }

    // segment ends: write alphainv for ending ray; fill empty rays in gaps
    if (v0 && rid.x != rid.y) {
        alphainv[rid.x] = e0;
        for (int q = rid.x + 1; q < rid.y; ++q) alphainv[q] = 1.0f;
    }
    if (v1 && rid.y != rid.z) {
        alphainv[rid.y] = e1;
        for (int q = rid.y + 1; q < rid.z; ++q) alphainv[q] = 1.0f;
    }
    if (v2 && rid.z != rid.w) {
        alphainv[rid.z] = e2;
        for (int q = rid.z + 1; q < rid.w; ++q) alphainv[q] = 1.0f;
    }
    if (v3 && rid.w != next3) {
        alphainv[rid.w] = e3;
        for (int q = rid.w + 1; q < next3; ++q) alphainv[q] = 1.0f;
    }
    if (idx0 == 0) {                    // rays before the first point
        for (int q = 0; q < rid.x; ++q) alphainv[q] = 1.0f;
    }
}

extern "C" void kernel_launch(void* const* d_in, const int* in_sizes, int n_in,
                              void* d_out, int out_size, void* d_ws, size_t ws_size,
                              hipStream_t stream) {
    const float* density  = (const float*)d_in[0];
    const float* shift    = (const float*)d_in[1];   // 1-element array
    const float* interval = (const float*)d_in[2];   // 1-element array
    const int*   ray_id   = (const int*)d_in[3];
    const int n_pts  = in_sizes[0];
    const int n_rays = out_size - n_pts;

    float* weights  = (float*)d_out;              // [n_pts]
    float* alphainv = (float*)d_out + n_pts;      // [n_rays]

    const int grid = (n_pts + 1023) / 1024;
    fused_alpha_weights<<<grid, 256, 0, stream>>>(
        density, ray_id, shift, interval, weights, alphainv, n_pts, n_rays);
}

// Round 10
// 24.472 us; speedup vs baseline: 1.9039x; 1.0994x over previous
//
#include <hip/hip_runtime.h>
#include <math.h>

// ---------------------------------------------------------------------------
// DirectVoxGO Raw2Alpha + Alphas2Weights (forward), single fused kernel.
//
// outputs (concatenated in d_out, float32):
//   weights[n_pts]         = alpha_j * T_j,  T_j = prod_{k<j} (1-alpha_k)
//   alphainv_last[n_rays]  = prod over ray of (1-alpha)  (empty rays -> 1.0)
//
// Structure: 1 block (256 thr) per 1024 consecutive points, 4 pts/thread.
// ALL loads issued up front (main quads, prev/next ray ids, and the whole
// 256-wide lookback window) -> one memory round-trip on the critical path,
// 2 barriers/block. Segmented multiplicative scan:
//   thread-local fold -> wave64 DPP (value,flag) scan -> 4-wave LDS combine.
// Cross-block carry recomputed locally from the speculatively-loaded window
// (ray head lies within 256 points before `base` w.h.p.; rare deeper heads
// take a correct block-uniform fallback loop).
// ---------------------------------------------------------------------------

#define LOG2E 1.4426950408889634f

typedef float vf4 __attribute__((ext_vector_type(4)));

__device__ __forceinline__ float exp2f_(float x) { return __builtin_amdgcn_exp2f(x); }
__device__ __forceinline__ float log2f_(float x) { return __builtin_amdgcn_logf(x); }
__device__ __forceinline__ float rsqf_(float x)  { return __builtin_amdgcn_rsqf(x); }

__device__ __forceinline__ float oma(float d, float sh2, float negc, bool fast) {
    const float y = fmaf(d, LOG2E, sh2);
    if (fast) return rsqf_(1.0f + exp2f_(y));
    const float sp = fmaxf(y, 0.f) + log2f_(1.f + exp2f_(-fabsf(y)));
    return exp2f_(negc * sp);
}

// Segmented-scan DPP step: combine src (earlier lanes, identity (1,0) when
// out-of-row/masked) into (V,F):  V = F ? V : Vs*V;  F |= Fs.
template <int CTRL, int RM>
__device__ __forceinline__ void seg_step(float& V, int& F) {
    const int vs_i = __builtin_amdgcn_update_dpp(
        0x3f800000, __builtin_bit_cast(int, V), CTRL, RM, 0xF, false);
    const int fs = __builtin_amdgcn_update_dpp(0, F, CTRL, RM, 0xF, false);
    const float vs = __builtin_bit_cast(float, vs_i);
    V = F ? V : vs * V;
    F = F | fs;
}

// Full-wave product, result broadcast to all lanes.
__device__ __forceinline__ float wave_prod_bcast(float x) {
#define STEPP(CTRL, RM)                                                        \
    { int t_ = __builtin_amdgcn_update_dpp(0x3f800000,                         \
          __builtin_bit_cast(int, x), CTRL, RM, 0xF, false);                   \
      x *= __builtin_bit_cast(float, t_); }
    STEPP(0x111, 0xF) STEPP(0x112, 0xF) STEPP(0x114, 0xF)
    STEPP(0x118, 0xF) STEPP(0x142, 0xA) STEPP(0x143, 0xC)
#undef STEPP
    return __builtin_bit_cast(float,
        __builtin_amdgcn_readlane(__builtin_bit_cast(int, x), 63));
}

// Full-wave int max, result broadcast to all lanes.
__device__ __forceinline__ int wave_imax_bcast(int x) {
#define STEPM(CTRL, RM)                                                        \
    { int t_ = __builtin_amdgcn_update_dpp((int)0x80000000, x, CTRL, RM,       \
                                           0xF, false);                        \
      x = (x > t_) ? x : t_; }
    STEPM(0x111, 0xF) STEPM(0x112, 0xF) STEPM(0x114, 0xF)
    STEPM(0x118, 0xF) STEPM(0x142, 0xA) STEPM(0x143, 0xC)
#undef STEPM
    return __builtin_amdgcn_readlane(x, 63);
}

__global__ void __launch_bounds__(256)
fused_alpha_weights(const float* __restrict__ density,
                    const int*   __restrict__ ray_id,
                    const float* __restrict__ shift_p,
                    const float* __restrict__ interval_p,
                    float* __restrict__ weights,
                    float* __restrict__ alphainv,
                    int n_pts, int n_rays) {
    __shared__ float s_wv[4];
    __shared__ int   s_wf[4];
    __shared__ float s_red[4];
    __shared__ int   s_redi[4];

    const int t    = threadIdx.x;
    const int lane = t & 63;
    const int wid  = t >> 6;
    const int base = blockIdx.x << 10;          // 1024 points per block
    const int idx0 = base + t * 4;

    const float shift = shift_p[0];
    const float c     = interval_p[0];
    const float sh2   = shift * LOG2E;
    const float negc  = -c;
    const bool  fast  = (c == 0.5f);

    // ================= phase 0: issue ALL loads up front =================
    int r[5]; float d[4];
    bool v0, v1, v2, v3;
    if (idx0 + 4 <= n_pts) {
        const int4   ri = *reinterpret_cast<const int4*>(ray_id + idx0);
        const float4 de = *reinterpret_cast<const float4*>(density + idx0);
        r[0] = ri.x; r[1] = ri.y; r[2] = ri.z; r[3] = ri.w;
        d[0] = de.x; d[1] = de.y; d[2] = de.z; d[3] = de.w;
        v0 = v1 = v2 = v3 = true;
    } else {
        #pragma unroll
        for (int k = 0; k < 4; ++k) {
            const int i = idx0 + k;
            const bool vv = (i < n_pts);
            r[k] = vv ? ray_id[i] : n_rays;     // sentinel past-end ray
            d[k] = vv ? density[i] : 0.0f;
        }
        v0 = (idx0 < n_pts); v1 = (idx0 + 1 < n_pts);
        v2 = (idx0 + 2 < n_pts); v3 = (idx0 + 3 < n_pts);
    }
    r[4] = (idx0 + 4 < n_pts) ? ray_id[idx0 + 4] : n_rays;   // next id
    const int rprev = (idx0 == 0) ? -1
                    : ((idx0 <= n_pts) ? ray_id[idx0 - 1] : n_rays);

    int w_id = 0; float w_den = 0.0f; int rfirst = 0;
    if (base > 0) {                              // speculative lookback window
        const int wi = base - 256 + t;
        w_id   = ray_id[wi];
        w_den  = density[wi];
        rfirst = ray_id[base];                   // ray active at block head
    }

    // ================= phase 1: per-element values & flags =================
    float a0 = oma(d[0], sh2, negc, fast);
    float a1 = oma(d[1], sh2, negc, fast);
    float a2 = oma(d[2], sh2, negc, fast);
    float a3 = oma(d[3], sh2, negc, fast);
    a0 = v0 ? a0 : 1.0f;  a1 = v1 ? a1 : 1.0f;
    a2 = v2 ? a2 : 1.0f;  a3 = v3 ? a3 : 1.0f;

    const int f0 = (r[0] != rprev);
    const int f1 = (r[1] != r[0]);
    const int f2 = (r[2] != r[1]);
    const int f3 = (r[3] != r[2]);

    // thread-local (V,F) fold over 4 elements
    float V = a0;  int F = f0;
    V = f1 ? a1 : V * a1;  F |= f1;
    V = f2 ? a2 : V * a2;  F |= f2;
    V = f3 ? a3 : V * a3;  F |= f3;

    // wave64 inclusive segmented scan (DPP, VALU-only)
    float Vi = V;  int Fi = F;
    seg_step<0x111, 0xF>(Vi, Fi);   // row_shr:1
    seg_step<0x112, 0xF>(Vi, Fi);   // row_shr:2
    seg_step<0x114, 0xF>(Vi, Fi);   // row_shr:4
    seg_step<0x118, 0xF>(Vi, Fi);   // row_shr:8
    seg_step<0x142, 0xA>(Vi, Fi);   // row_bcast:15 -> rows 1,3
    seg_step<0x143, 0xC>(Vi, Fi);   // row_bcast:31 -> rows 2,3

    // ================= phase 2: cross-wave + head carry (2 barriers) ======
    if (lane == 63) { s_wv[wid] = Vi; s_wf[wid] = Fi; }
    if (base > 0) {
        const int cand = (w_id != rfirst) ? t : -1;
        const int wm = wave_imax_bcast(cand);
        if (lane == 0) s_redi[wid] = wm;
    }
    __syncthreads();                             // barrier 1

    float carry0 = 1.0f;
    if (base > 0) {
        int m = s_redi[0];
        m = (s_redi[1] > m) ? s_redi[1] : m;
        m = (s_redi[2] > m) ? s_redi[2] : m;
        m = (s_redi[3] > m) ? s_redi[3] : m;
        // m >= 0: ray head at base-256+m+1; window product over (m, 256).
        // m < 0 (freak): whole window inside segment; extend further below.
        float aa = oma(w_den, sh2, negc, fast);
        if (m >= 0 && t <= m) aa = 1.0f;
        const float wp = wave_prod_bcast(aa);
        if (lane == 0) s_red[wid] = wp;
        __syncthreads();                         // barrier 2
        carry0 = s_red[0] * s_red[1] * s_red[2] * s_red[3];

        if (m < 0) {                             // freak ray: walk further back
            int lo = base - 256;                 // [s0, lo) still missing
            int s0 = -1;
            while (s0 < 0) {
                const int wstart = lo - 256;
                const int i = wstart + t;
                const int vv = (i >= 0) ? ray_id[i] : -1;
                const int c2 = (vv != rfirst) ? t : -1;
                const int wm2 = wave_imax_bcast(c2);
                if (lane == 0) s_redi[wid] = wm2;
                __syncthreads();
                int m2 = s_redi[0];
                m2 = (s_redi[1] > m2) ? s_redi[1] : m2;
                m2 = (s_redi[2] > m2) ? s_redi[2] : m2;
                m2 = (s_redi[3] > m2) ? s_redi[3] : m2;
                __syncthreads();
                if (m2 >= 0) s0 = wstart + m2 + 1; else lo = wstart;
            }
            for (int off = s0; off < base - 256; off += 256) {
                const int i = off + t;
                const float aa2 = (i < base - 256)
                                ? oma(density[i], sh2, negc, fast) : 1.0f;
                const float wp2 = wave_prod_bcast(aa2);
                if (lane == 0) s_red[wid] = wp2;
                __syncthreads();
                carry0 *= s_red[0] * s_red[1] * s_red[2] * s_red[3];
                __syncthreads();
            }
        }
    }

    // exclusive pair for this thread (within wave)
    float Vx = __shfl_up(Vi, 1, 64);
    int   Fx = __shfl_up(Fi, 1, 64);
    if (lane == 0) { Vx = 1.0f; Fx = 0; }

    // fold block head carry + lower waves + lower lanes
    float Ev = carry0;
    #pragma unroll
    for (int w2 = 0; w2 < 3; ++w2) {
        if (w2 < wid) {
            const float bv = s_wv[w2];  const int bf = s_wf[w2];
            Ev = bf ? bv : Ev * bv;
        }
    }
    Ev = Fx ? Vx : Ev * Vx;            // exclusive transmittance at elem 0

    // ================= phase 3: T chain, weights, alphainv =================
    const float T0 = f0 ? 1.0f : Ev;
    const float e0 = T0 * a0;
    const float T1 = f1 ? 1.0f : e0;
    const float e1 = T1 * a1;
    const float T2 = f2 ? 1.0f : e1;
    const float e2 = T2 * a2;
    const float T3 = f3 ? 1.0f : e2;
    const float e3 = T3 * a3;

    if (idx0 + 4 <= n_pts) {
        vf4 w = { T0 - e0, T1 - e1, T2 - e2, T3 - e3 };
        __builtin_nontemporal_store(w, reinterpret_cast<vf4*>(weights + idx0));
    } else {
        if (v0) weights[idx0]     = T0 - e0;
        if (v1) weights[idx0 + 1] = T1 - e1;
        if (v2) weights[idx0 + 2] = T2 - e2;
        if (v3) weights[idx0 + 3] = T3 - e3;
    }

    // segment ends: write alphainv for ending ray; fill empty rays in gaps
    if (v0 && r[0] != r[1]) {
        alphainv[r[0]] = e0;
        for (int q = r[0] + 1; q < r[1]; ++q) alphainv[q] = 1.0f;
    }
    if (v1 && r[1] != r[2]) {
        alphainv[r[1]] = e1;
        for (int q = r[1] + 1; q < r[2]; ++q) alphainv[q] = 1.0f;
    }
    if (v2 && r[2] != r[3]) {
        alphainv[r[2]] = e2;
        for (int q = r[2] + 1; q < r[3]; ++q) alphainv[q] = 1.0f;
    }
    if (v3 && r[3] != r[4]) {
        alphainv[r[3]] = e3;
        for (int q = r[3] + 1; q < r[4]; ++q) alphainv[q] = 1.0f;
    }
    if (idx0 == 0) {                    // rays before the first point
        for (int q = 0; q < r[0]; ++q) alphainv[q] = 1.0f;
    }
}

extern "C" void kernel_launch(void* const* d_in, const int* in_sizes, int n_in,
                              void* d_out, int out_size, void* d_ws, size_t ws_size,
                              hipStream_t stream) {
    const float* density  = (const float*)d_in[0];
    const float* shift    = (const float*)d_in[1];   // 1-element array
    const float* interval = (const float*)d_in[2];   // 1-element array
    const int*   ray_id   = (const int*)d_in[3];
    const int n_pts  = in_sizes[0];
    const int n_rays = out_size - n_pts;

    float* weights  = (float*)d_out;              // [n_pts]
    float* alphainv = (float*)d_out + n_pts;      // [n_rays]

    const int grid = (n_pts + 1023) / 1024;
    fused_alpha_weights<<<grid, 256, 0, stream>>>(
        density, ray_id, shift, interval, weights, alphainv, n_pts, n_rays);
}

// Round 11
// 22.734 us; speedup vs baseline: 2.0495x; 1.0765x over previous
//
#include <hip/hip_runtime.h>
#include <math.h>

// ---------------------------------------------------------------------------
// DirectVoxGO Raw2Alpha + Alphas2Weights (forward), single fused kernel.
//
// outputs (concatenated in d_out, float32):
//   weights[n_pts]         = alpha_j * T_j,  T_j = prod_{k<j} (1-alpha_k)
//   alphainv_last[n_rays]  = prod over ray of (1-alpha)  (empty rays -> 1.0)
//
// Structure: 1 block (256 thr) per 2048 consecutive points, 8 pts/thread.
// XCD-aware bijective block swizzle so data-neighbor blocks share an XCD's
// L2 -> the 256-point lookback window (to recompute the straddling ray's
// head product) is an L2 hit. All loads issued up front; 2 barriers/block.
// Segmented multiplicative scan: thread-local fold -> wave64 DPP (value,
// flag) scan -> 4-wave LDS combine -> local head-carry fold.
// ---------------------------------------------------------------------------

#define LOG2E 1.4426950408889634f
#define EPT   8                     // elements per thread
#define BPTS  (256 * EPT)           // points per block = 2048
#define NXCD  8

typedef float vf4 __attribute__((ext_vector_type(4)));

__device__ __forceinline__ float exp2f_(float x) { return __builtin_amdgcn_exp2f(x); }
__device__ __forceinline__ float log2f_(float x) { return __builtin_amdgcn_logf(x); }
__device__ __forceinline__ float rsqf_(float x)  { return __builtin_amdgcn_rsqf(x); }

__device__ __forceinline__ float oma(float d, float sh2, float negc, bool fast) {
    const float y = fmaf(d, LOG2E, sh2);
    if (fast) return rsqf_(1.0f + exp2f_(y));
    const float sp = fmaxf(y, 0.f) + log2f_(1.f + exp2f_(-fabsf(y)));
    return exp2f_(negc * sp);
}

// Segmented-scan DPP step: combine src (earlier lanes, identity (1,0) when
// out-of-row/masked) into (V,F):  V = F ? V : Vs*V;  F |= Fs.
template <int CTRL, int RM>
__device__ __forceinline__ void seg_step(float& V, int& F) {
    const int vs_i = __builtin_amdgcn_update_dpp(
        0x3f800000, __builtin_bit_cast(int, V), CTRL, RM, 0xF, false);
    const int fs = __builtin_amdgcn_update_dpp(0, F, CTRL, RM, 0xF, false);
    const float vs = __builtin_bit_cast(float, vs_i);
    V = F ? V : vs * V;
    F = F | fs;
}

// Full-wave product, result broadcast to all lanes.
__device__ __forceinline__ float wave_prod_bcast(float x) {
#define STEPP(CTRL, RM)                                                        \
    { int t_ = __builtin_amdgcn_update_dpp(0x3f800000,                         \
          __builtin_bit_cast(int, x), CTRL, RM, 0xF, false);                   \
      x *= __builtin_bit_cast(float, t_); }
    STEPP(0x111, 0xF) STEPP(0x112, 0xF) STEPP(0x114, 0xF)
    STEPP(0x118, 0xF) STEPP(0x142, 0xA) STEPP(0x143, 0xC)
#undef STEPP
    return __builtin_bit_cast(float,
        __builtin_amdgcn_readlane(__builtin_bit_cast(int, x), 63));
}

// Full-wave int max, result broadcast to all lanes.
__device__ __forceinline__ int wave_imax_bcast(int x) {
#define STEPM(CTRL, RM)                                                        \
    { int t_ = __builtin_amdgcn_update_dpp((int)0x80000000, x, CTRL, RM,       \
                                           0xF, false);                        \
      x = (x > t_) ? x : t_; }
    STEPM(0x111, 0xF) STEPM(0x112, 0xF) STEPM(0x114, 0xF)
    STEPM(0x118, 0xF) STEPM(0x142, 0xA) STEPM(0x143, 0xC)
#undef STEPM
    return __builtin_amdgcn_readlane(x, 63);
}

__global__ void __launch_bounds__(256)
fused_alpha_weights(const float* __restrict__ density,
                    const int*   __restrict__ ray_id,
                    const float* __restrict__ shift_p,
                    const float* __restrict__ interval_p,
                    float* __restrict__ weights,
                    float* __restrict__ alphainv,
                    int n_pts, int n_rays) {
    __shared__ float s_wv[4];
    __shared__ int   s_wf[4];
    __shared__ float s_red[4];
    __shared__ int   s_redi[4];

    const int t    = threadIdx.x;
    const int lane = t & 63;
    const int wid  = t >> 6;

    // XCD-aware bijective swizzle (m204): XCD k owns a contiguous data chunk,
    // so data-neighbor blocks are consecutive launches on the SAME XCD.
    const int nwg  = gridDim.x;
    const int orig = blockIdx.x;
    const int qq   = nwg / NXCD, rr = nwg % NXCD;
    const int xcd  = orig % NXCD;
    const int blk  = (xcd < rr ? xcd * (qq + 1) : rr * (qq + 1) + (xcd - rr) * qq)
                   + orig / NXCD;

    const int base = blk * BPTS;
    const int idx0 = base + t * EPT;

    const float shift = shift_p[0];
    const float c     = interval_p[0];
    const float sh2   = shift * LOG2E;
    const float negc  = -c;
    const bool  fast  = (c == 0.5f);

    // ================= phase 0: issue ALL loads up front =================
    int r[EPT + 1]; float d[EPT]; bool v[EPT];
    if (idx0 + EPT <= n_pts) {
        const int4   ri0 = *reinterpret_cast<const int4*>(ray_id + idx0);
        const int4   ri1 = *reinterpret_cast<const int4*>(ray_id + idx0 + 4);
        const float4 de0 = *reinterpret_cast<const float4*>(density + idx0);
        const float4 de1 = *reinterpret_cast<const float4*>(density + idx0 + 4);
        r[0] = ri0.x; r[1] = ri0.y; r[2] = ri0.z; r[3] = ri0.w;
        r[4] = ri1.x; r[5] = ri1.y; r[6] = ri1.z; r[7] = ri1.w;
        d[0] = de0.x; d[1] = de0.y; d[2] = de0.z; d[3] = de0.w;
        d[4] = de1.x; d[5] = de1.y; d[6] = de1.z; d[7] = de1.w;
        #pragma unroll
        for (int k = 0; k < EPT; ++k) v[k] = true;
    } else {
        #pragma unroll
        for (int k = 0; k < EPT; ++k) {
            const int i = idx0 + k;
            v[k] = (i < n_pts);
            r[k] = v[k] ? ray_id[i] : n_rays;    // sentinel past-end ray
            d[k] = v[k] ? density[i] : 0.0f;
        }
    }
    r[EPT] = (idx0 + EPT < n_pts) ? ray_id[idx0 + EPT] : n_rays;
    const int rprev = (idx0 == 0) ? -1
                    : ((idx0 <= n_pts) ? ray_id[idx0 - 1] : n_rays);

    int w_id = 0; float w_den = 0.0f; int rfirst = 0;
    if (base > 0) {                              // speculative lookback window
        const int wi = base - 256 + t;
        w_id   = ray_id[wi];
        w_den  = density[wi];
        rfirst = ray_id[base];                   // ray active at block head
    }

    // ================= phase 1: per-element values & flags =================
    float a[EPT]; int f[EPT];
    #pragma unroll
    for (int k = 0; k < EPT; ++k) {
        const float av = oma(d[k], sh2, negc, fast);
        a[k] = v[k] ? av : 1.0f;
        f[k] = (k == 0) ? (r[0] != rprev) : (r[k] != r[k - 1]);
    }

    // thread-local (V,F) fold over EPT elements
    float V = a[0];  int F = f[0];
    #pragma unroll
    for (int k = 1; k < EPT; ++k) {
        V = f[k] ? a[k] : V * a[k];
        F |= f[k];
    }

    // wave64 inclusive segmented scan (DPP, VALU-only)
    float Vi = V;  int Fi = F;
    seg_step<0x111, 0xF>(Vi, Fi);   // row_shr:1
    seg_step<0x112, 0xF>(Vi, Fi);   // row_shr:2
    seg_step<0x114, 0xF>(Vi, Fi);   // row_shr:4
    seg_step<0x118, 0xF>(Vi, Fi);   // row_shr:8
    seg_step<0x142, 0xA>(Vi, Fi);   // row_bcast:15 -> rows 1,3
    seg_step<0x143, 0xC>(Vi, Fi);   // row_bcast:31 -> rows 2,3

    // ================= phase 2: cross-wave + head carry (2 barriers) ======
    if (lane == 63) { s_wv[wid] = Vi; s_wf[wid] = Fi; }
    if (base > 0) {
        const int cand = (w_id != rfirst) ? t : -1;
        const int wm = wave_imax_bcast(cand);
        if (lane == 0) s_redi[wid] = wm;
    }
    __syncthreads();                             // barrier 1

    float carry0 = 1.0f;
    if (base > 0) {
        int m = s_redi[0];
        m = (s_redi[1] > m) ? s_redi[1] : m;
        m = (s_redi[2] > m) ? s_redi[2] : m;
        m = (s_redi[3] > m) ? s_redi[3] : m;
        // m >= 0: ray head at base-256+m+1; window product over (m, 256).
        float aa = oma(w_den, sh2, negc, fast);
        if (m >= 0 && t <= m) aa = 1.0f;
        const float wp = wave_prod_bcast(aa);
        if (lane == 0) s_red[wid] = wp;
        __syncthreads();                         // barrier 2
        carry0 = s_red[0] * s_red[1] * s_red[2] * s_red[3];

        if (m < 0) {                             // freak ray: walk further back
            int lo = base - 256;                 // [s0, lo) still missing
            int s0 = -1;
            while (s0 < 0) {
                const int wstart = lo - 256;
                const int i = wstart + t;
                const int vv = (i >= 0) ? ray_id[i] : -1;
                const int c2 = (vv != rfirst) ? t : -1;
                const int wm2 = wave_imax_bcast(c2);
                if (lane == 0) s_redi[wid] = wm2;
                __syncthreads();
                int m2 = s_redi[0];
                m2 = (s_redi[1] > m2) ? s_redi[1] : m2;
                m2 = (s_redi[2] > m2) ? s_redi[2] : m2;
                m2 = (s_redi[3] > m2) ? s_redi[3] : m2;
                __syncthreads();
                if (m2 >= 0) s0 = wstart + m2 + 1; else lo = wstart;
            }
            for (int off = s0; off < base - 256; off += 256) {
                const int i = off + t;
                const float aa2 = (i < base - 256)
                                ? oma(density[i], sh2, negc, fast) : 1.0f;
                const float wp2 = wave_prod_bcast(aa2);
                if (lane == 0) s_red[wid] = wp2;
                __syncthreads();
                carry0 *= s_red[0] * s_red[1] * s_red[2] * s_red[3];
                __syncthreads();
            }
        }
    }

    // exclusive pair for this thread (within wave)
    float Vx = __shfl_up(Vi, 1, 64);
    int   Fx = __shfl_up(Fi, 1, 64);
    if (lane == 0) { Vx = 1.0f; Fx = 0; }

    // fold block head carry + lower waves + lower lanes
    float Ev = carry0;
    #pragma unroll
    for (int w2 = 0; w2 < 3; ++w2) {
        if (w2 < wid) {
            const float bv = s_wv[w2];  const int bf = s_wf[w2];
            Ev = bf ? bv : Ev * bv;
        }
    }
    Ev = Fx ? Vx : Ev * Vx;            // exclusive transmittance at elem 0

    // ================= phase 3: T chain, weights, alphainv =================
    float T[EPT], e[EPT];
    float prev = Ev;
    #pragma unroll
    for (int k = 0; k < EPT; ++k) {
        T[k] = f[k] ? 1.0f : prev;
        e[k] = T[k] * a[k];
        prev = e[k];
    }

    if (idx0 + EPT <= n_pts) {
        vf4 w0 = { T[0] - e[0], T[1] - e[1], T[2] - e[2], T[3] - e[3] };
        vf4 w1 = { T[4] - e[4], T[5] - e[5], T[6] - e[6], T[7] - e[7] };
        __builtin_nontemporal_store(w0, reinterpret_cast<vf4*>(weights + idx0));
        __builtin_nontemporal_store(w1, reinterpret_cast<vf4*>(weights + idx0 + 4));
    } else {
        #pragma unroll
        for (int k = 0; k < EPT; ++k)
            if (v[k]) weights[idx0 + k] = T[k] - e[k];
    }

    // segment ends: write alphainv for ending ray; fill empty rays in gaps
    #pragma unroll
    for (int k = 0; k < EPT; ++k) {
        if (v[k] && r[k] != r[k + 1]) {
            alphainv[r[k]] = e[k];
            for (int q = r[k] + 1; q < r[k + 1]; ++q) alphainv[q] = 1.0f;
        }
    }
    if (idx0 == 0) {                    // rays before the first point
        for (int q = 0; q < r[0]; ++q) alphainv[q] = 1.0f;
    }
}

extern "C" void kernel_launch(void* const* d_in, const int* in_sizes, int n_in,
                              void* d_out, int out_size, void* d_ws, size_t ws_size,
                              hipStream_t stream) {
    const float* density  = (const float*)d_in[0];
    const float* shift    = (const float*)d_in[1];   // 1-element array
    const float* interval = (const float*)d_in[2];   // 1-element array
    const int*   ray_id   = (const int*)d_in[3];
    const int n_pts  = in_sizes[0];
    const int n_rays = out_size - n_pts;

    float* weights  = (float*)d_out;              // [n_pts]
    float* alphainv = (float*)d_out + n_pts;      // [n_rays]

    const int grid = (n_pts + BPTS - 1) / BPTS;
    fused_alpha_weights<<<grid, 256, 0, stream>>>(
        density, ray_id, shift, interval, weights, alphainv, n_pts, n_rays);
}